// Round 1
// baseline (312.808 us; speedup 1.0000x reference)
//
#include <hip/hip_runtime.h>
#include <cstdint>
#include <cstddef>

// ---------------------------------------------------------------------------
// SparseMHADecoder: B=2, LQ=4096, LKV=2048, D=1024, H=16, d=64, span=16, stride=2
//   Q = q@Wq, K = k@Wk, V = v@Wv  (fp16 MFMA GEMMs, f32 accum)
//   scores masked to 0 <= q - 2*col < 16 ; softmax over the QUERY axis (per col)
//   ctx[q] = sum over <=8 valid cols of attn * V   (gather, no atomics)
//   out = ctx@Wo (f32 output)
// fp16 (not bf16) everywhere: score abs-error ~0.01 -> attn err ~1% -> out
// absmax ~0.03 vs threshold 0.084. bf16 would be borderline-fail.
// ---------------------------------------------------------------------------

typedef _Float16 f16;
typedef _Float16 f16x4 __attribute__((ext_vector_type(4)));
typedef _Float16 f16x8 __attribute__((ext_vector_type(8)));
typedef float v4f __attribute__((ext_vector_type(4)));

#define B_  2
#define LQ_ 4096
#define LKV_ 2048
#define DMODEL 1024
#define NH 16
#define HD 64
#define SPAN 16
#define STRIDE 2

__device__ __forceinline__ void async_copy16(const f16* g, f16* l) {
    __builtin_amdgcn_global_load_lds((const __attribute__((address_space(1))) void*)g,
                                     (__attribute__((address_space(3))) void*)l, 16, 0, 0);
}

// ---------------- f32 -> f16 elementwise convert (n % 4 == 0) ----------------
__global__ void cvt_f32_f16(const float* __restrict__ in, f16* __restrict__ out, int n) {
    int i = (blockIdx.x * 256 + threadIdx.x) * 4;
    if (i < n) {
        float4 v = *(const float4*)(in + i);
        f16x4 o = {(f16)v.x, (f16)v.y, (f16)v.z, (f16)v.w};
        *(f16x4*)(out + i) = o;
    }
}

// ------------- transpose + convert: Wt[n][k] = (f16) W[k][n] -----------------
__global__ void transpose_cvt(const float* __restrict__ W, f16* __restrict__ Wt,
                              int R, int C) {
    __shared__ float tile[64][65];
    const int r0 = blockIdx.y * 64, c0 = blockIdx.x * 64;
    const int tx = threadIdx.x, ty = threadIdx.y;  // (64,4)
    for (int i = ty; i < 64; i += 4)
        tile[i][tx] = W[(long)(r0 + i) * C + c0 + tx];
    __syncthreads();
    for (int i = ty; i < 64; i += 4)
        Wt[(long)(c0 + i) * R + r0 + tx] = (f16)tile[tx][i];
}

// ---------------- fp16 GEMM, C[m][n] = sum_k A[m][k]*Bt[n][k] ----------------
// m97 structure: 128x128 tile, BK=32, global_load_lds(16B), 16x16x32 f16 MFMA.
// M,N,K all multiples of 128 here -> no bounds checks.
template <bool OUT_F32>
__global__ __launch_bounds__(256, 2)
void gemm_bt_f16(const f16* __restrict__ A, const f16* __restrict__ Bt,
                 void* __restrict__ Cv, int M, int N, int K) {
    __shared__ f16 As[128 * 32];
    __shared__ f16 Bs[128 * 32];
    const int t = threadIdx.x;
    const int lane = t & 63;
    const int w = t >> 6;          // wave 0..3
    const int wm = w >> 1, wn = w & 1;
    const long rowBase = (long)blockIdx.y * 128;
    const long colBase = (long)blockIdx.x * 128;
    const int qrow = lane & 15;    // fragment row/col index
    const int quad = lane >> 4;    // k-pack selector

    v4f acc[4][4] = {};

    // staging: wave w covers rows [w*32, w*32+32) of each 128x32 tile,
    // LDS dest = wave-uniform base + lane*16B (required by global_load_lds)
    const int srow = w * 32 + (lane >> 2);
    const int scol = (lane & 3) * 8;
    const f16* aptr = A + (rowBase + srow) * (long)K + scol;
    const f16* bptr = Bt + (colBase + srow) * (long)K + scol;
    f16* lA0 = &As[srow * 32 + scol];
    f16* lA1 = &As[(srow + 16) * 32 + scol];
    f16* lB0 = &Bs[srow * 32 + scol];
    f16* lB1 = &Bs[(srow + 16) * 32 + scol];

    for (int k0 = 0; k0 < K; k0 += 32) {
        async_copy16(aptr + k0, lA0);
        async_copy16(aptr + 16 * (long)K + k0, lA1);
        async_copy16(bptr + k0, lB0);
        async_copy16(bptr + 16 * (long)K + k0, lB1);
        __syncthreads();  // drains vmcnt(0): staged tile visible
        f16x8 af[4], bf[4];
#pragma unroll
        for (int mt = 0; mt < 4; ++mt)
            af[mt] = *(const f16x8*)(&As[(wm * 64 + mt * 16 + qrow) * 32 + quad * 8]);
#pragma unroll
        for (int nt = 0; nt < 4; ++nt)
            bf[nt] = *(const f16x8*)(&Bs[(wn * 64 + nt * 16 + qrow) * 32 + quad * 8]);
#pragma unroll
        for (int mt = 0; mt < 4; ++mt)
#pragma unroll
            for (int nt = 0; nt < 4; ++nt)
                acc[mt][nt] = __builtin_amdgcn_mfma_f32_16x16x32_f16(af[mt], bf[nt],
                                                                     acc[mt][nt], 0, 0, 0);
        __syncthreads();  // all reads done before next stage overwrites
    }

    // C/D layout (m89-verified): row = m = quad*4 + r, col = n = lane&15
#pragma unroll
    for (int mt = 0; mt < 4; ++mt)
#pragma unroll
        for (int nt = 0; nt < 4; ++nt) {
            const long col = colBase + wn * 64 + nt * 16 + qrow;
#pragma unroll
            for (int r = 0; r < 4; ++r) {
                const long row = rowBase + wm * 64 + mt * 16 + quad * 4 + r;
                if (OUT_F32)
                    ((float*)Cv)[row * (long)N + col] = acc[mt][nt][r];
                else
                    ((f16*)Cv)[row * (long)N + col] = (f16)acc[mt][nt][r];
            }
        }
}

// -------- per-column scores + softmax over the 16 valid query rows ----------
// grid (LKV, B), block 256 = 16 heads x 16 row-offsets j; q = 2*col + j
__global__ __launch_bounds__(256)
void attn_scores(const f16* __restrict__ Q, const f16* __restrict__ Km,
                 float* __restrict__ attnw) {
    const int c = blockIdx.x, b = blockIdx.y;
    const int t = threadIdx.x;
    const int h = t >> 4, j = t & 15;
    __shared__ float Ks[DMODEL];
    const f16* krow = Km + (long)(b * LKV_ + c) * DMODEL;
    {
        f16x4 kv = *(const f16x4*)(krow + t * 4);
        Ks[t * 4 + 0] = (float)kv[0];
        Ks[t * 4 + 1] = (float)kv[1];
        Ks[t * 4 + 2] = (float)kv[2];
        Ks[t * 4 + 3] = (float)kv[3];
    }
    __syncthreads();
    const int q = STRIDE * c + j;
    float s = -1e30f;
    if (q < LQ_) {
        const f16* qrow = Q + (long)(b * LQ_ + q) * DMODEL + h * HD;
        float a = 0.f;
#pragma unroll
        for (int d = 0; d < HD; d += 8) {
            f16x8 qv = *(const f16x8*)(qrow + d);
#pragma unroll
            for (int u = 0; u < 8; ++u) a += (float)qv[u] * Ks[h * HD + d + u];
        }
        s = a;
    }
    // softmax over j: 16 contiguous lanes share h (xor<16 stays in group)
    float m = s;
#pragma unroll
    for (int o = 1; o < 16; o <<= 1) m = fmaxf(m, __shfl_xor(m, o, 64));
    float p = (q < LQ_) ? __expf(s - m) : 0.f;
    float sum = p;
#pragma unroll
    for (int o = 1; o < 16; o <<= 1) sum += __shfl_xor(sum, o, 64);
    attnw[(long)((b * LKV_ + c) * NH + h) * SPAN + j] = p / sum;
}

// ---- ctx[b,q,h,:] = sum_i attn[b, q/2 - i, h, (q&1)+2i] * V[b, q/2-i, h, :] ----
// grid (LQ, B), block 256 = 4 head-groups x 64 dims; each thread does 4 heads
__global__ __launch_bounds__(256)
void ctx_gather(const float* __restrict__ attnw, const f16* __restrict__ V,
                f16* __restrict__ ctx) {
    const int qi = blockIdx.x, b = blockIdx.y;
    const int t = threadIdx.x;
    const int d = t & 63;
    const int hg = t >> 6;
    const int kmax = qi >> 1;
    const int j0 = qi & 1;
    float acc[4] = {0.f, 0.f, 0.f, 0.f};
#pragma unroll
    for (int i = 0; i < SPAN / STRIDE; ++i) {
        const int k = kmax - i;
        if (k < 0) break;
        const int j = j0 + STRIDE * i;
        const float* arow = attnw + (long)(b * LKV_ + k) * (NH * SPAN);
        const f16* vrow = V + (long)(b * LKV_ + k) * DMODEL;
#pragma unroll
        for (int hh = 0; hh < 4; ++hh) {
            const int h = hg * 4 + hh;
            acc[hh] += arow[h * SPAN + j] * (float)vrow[h * HD + d];
        }
    }
    f16* crow = ctx + (long)(b * LQ_ + qi) * DMODEL;
#pragma unroll
    for (int hh = 0; hh < 4; ++hh) {
        const int h = hg * 4 + hh;
        crow[h * HD + d] = (f16)acc[hh];
    }
}

// ---------------------------------------------------------------------------
extern "C" void kernel_launch(void* const* d_in, const int* in_sizes, int n_in,
                              void* d_out, int out_size, void* d_ws, size_t ws_size,
                              hipStream_t stream) {
    const float* q  = (const float*)d_in[0];
    const float* k  = (const float*)d_in[1];
    const float* v  = (const float*)d_in[2];
    const float* Wq = (const float*)d_in[3];
    const float* Wk = (const float*)d_in[4];
    const float* Wv = (const float*)d_in[5];
    const float* Wo = (const float*)d_in[6];
    // d_in[7]=span(16), d_in[8]=stride(2): fixed by setup_inputs, hard-coded.
    float* out = (float*)d_out;

    const size_t NQ = (size_t)B_ * LQ_ * DMODEL;   // 8388608
    const size_t NKV = (size_t)B_ * LKV_ * DMODEL; // 4194304
    const size_t NW = (size_t)DMODEL * DMODEL;     // 1048576

    char* p = (char*)d_ws;
    f16* qh  = (f16*)p; p += NQ * 2;
    f16* kh  = (f16*)p; p += NKV * 2;
    f16* vh  = (f16*)p; p += NKV * 2;
    f16* WqT = (f16*)p; p += NW * 2;
    f16* WkT = (f16*)p; p += NW * 2;
    f16* WvT = (f16*)p; p += NW * 2;
    f16* WoT = (f16*)p; p += NW * 2;
    f16* Qh  = (f16*)p; p += NQ * 2;
    f16* Kh  = (f16*)p; p += NKV * 2;
    f16* Vh  = (f16*)p; p += NKV * 2;
    float* attnw = (float*)p; p += (size_t)B_ * LKV_ * NH * SPAN * 4;  // 4 MB
    f16* ctxh = (f16*)p; p += NQ * 2;  // total ~92 MB

    cvt_f32_f16<<<dim3((unsigned)(NQ / 4 / 256)), 256, 0, stream>>>(q, qh, (int)NQ);
    cvt_f32_f16<<<dim3((unsigned)(NKV / 4 / 256)), 256, 0, stream>>>(k, kh, (int)NKV);
    cvt_f32_f16<<<dim3((unsigned)(NKV / 4 / 256)), 256, 0, stream>>>(v, vh, (int)NKV);

    dim3 tb(64, 4), tg(16, 16);
    transpose_cvt<<<tg, tb, 0, stream>>>(Wq, WqT, DMODEL, DMODEL);
    transpose_cvt<<<tg, tb, 0, stream>>>(Wk, WkT, DMODEL, DMODEL);
    transpose_cvt<<<tg, tb, 0, stream>>>(Wv, WvT, DMODEL, DMODEL);
    transpose_cvt<<<tg, tb, 0, stream>>>(Wo, WoT, DMODEL, DMODEL);

    gemm_bt_f16<false><<<dim3(DMODEL / 128, B_ * LQ_ / 128), 256, 0, stream>>>(
        qh, WqT, (void*)Qh, B_ * LQ_, DMODEL, DMODEL);
    gemm_bt_f16<false><<<dim3(DMODEL / 128, B_ * LKV_ / 128), 256, 0, stream>>>(
        kh, WkT, (void*)Kh, B_ * LKV_, DMODEL, DMODEL);
    gemm_bt_f16<false><<<dim3(DMODEL / 128, B_ * LKV_ / 128), 256, 0, stream>>>(
        vh, WvT, (void*)Vh, B_ * LKV_, DMODEL, DMODEL);

    attn_scores<<<dim3(LKV_, B_), 256, 0, stream>>>(Qh, Kh, attnw);
    ctx_gather<<<dim3(LQ_, B_), 256, 0, stream>>>(attnw, Vh, ctxh);

    gemm_bt_f16<true><<<dim3(DMODEL / 128, B_ * LQ_ / 128), 256, 0, stream>>>(
        ctxh, WoT, (void*)out, B_ * LQ_, DMODEL, DMODEL);
}

// Round 3
// 266.969 us; speedup vs baseline: 1.1717x; 1.1717x over previous
//
#include <hip/hip_runtime.h>
#include <cstdint>
#include <cstddef>

// ---------------------------------------------------------------------------
// SparseMHADecoder: B=2, LQ=4096, LKV=2048, D=1024, H=16, d=64, span=16, stride=2
// R3: fix R2's NaN — attn_scores Q staging only covered D<256 (heads 0-3);
//     heads 4-15 read uninitialized LDS (stale f16 can be NaN) -> NaN output.
//     Now each thread stages 4x16 f16 chunks covering the full 1024-elem row.
// Everything else = R2 structure (6 launches), R1-verified numerics (fp16).
// ---------------------------------------------------------------------------

typedef _Float16 f16;
typedef _Float16 f16x4 __attribute__((ext_vector_type(4)));
typedef _Float16 f16x8 __attribute__((ext_vector_type(8)));
typedef float v4f __attribute__((ext_vector_type(4)));

#define B_  2
#define LQ_ 4096
#define LKV_ 2048
#define DMODEL 1024
#define NH 16
#define HD 64
#define SPAN 16
#define STRIDE 2

#define NQ_ELEMS  ((size_t)B_ * LQ_ * DMODEL)   // 8388608
#define NKV_ELEMS ((size_t)B_ * LKV_ * DMODEL)  // 4194304

__device__ __forceinline__ void async_copy16(const f16* g, f16* l) {
    __builtin_amdgcn_global_load_lds((const __attribute__((address_space(1))) void*)g,
                                     (__attribute__((address_space(3))) void*)l, 16, 0, 0);
}

// ---------------- fused f32 -> f16 convert of q,k,v (one launch) -------------
__global__ void cvt_all(const float* __restrict__ q, const float* __restrict__ k,
                        const float* __restrict__ v, f16* __restrict__ qh,
                        f16* __restrict__ kh, f16* __restrict__ vh) {
    size_t i = ((size_t)blockIdx.x * 256 + threadIdx.x) * 4;
    const float* src;
    f16* dst;
    if (i < NQ_ELEMS) {
        src = q + i; dst = qh + i;
    } else if (i < NQ_ELEMS + NKV_ELEMS) {
        src = k + (i - NQ_ELEMS); dst = kh + (i - NQ_ELEMS);
    } else {
        src = v + (i - NQ_ELEMS - NKV_ELEMS); dst = vh + (i - NQ_ELEMS - NKV_ELEMS);
    }
    float4 x = *(const float4*)src;
    f16x4 o = {(f16)x.x, (f16)x.y, (f16)x.z, (f16)x.w};
    *(f16x4*)dst = o;
}

// -------- fused transpose+convert of 4 weights: Wt[n][k] = (f16)W[k][n] ------
__global__ void transpose_all(const float* __restrict__ W0, const float* __restrict__ W1,
                              const float* __restrict__ W2, const float* __restrict__ W3,
                              f16* __restrict__ T0, f16* __restrict__ T1,
                              f16* __restrict__ T2, f16* __restrict__ T3) {
    const float* W;
    f16* Wt;
    switch (blockIdx.z) {
        case 0: W = W0; Wt = T0; break;
        case 1: W = W1; Wt = T1; break;
        case 2: W = W2; Wt = T2; break;
        default: W = W3; Wt = T3; break;
    }
    __shared__ float tile[64][65];
    const int r0 = blockIdx.y * 64, c0 = blockIdx.x * 64;
    const int tx = threadIdx.x, ty = threadIdx.y;  // (64,4)
    for (int i = ty; i < 64; i += 4)
        tile[i][tx] = W[(long)(r0 + i) * DMODEL + c0 + tx];
    __syncthreads();
    for (int i = ty; i < 64; i += 4)
        Wt[(long)(c0 + i) * DMODEL + r0 + tx] = (f16)tile[tx][i];
}

// ---------------- fp16 GEMM body, C[m][n] = sum_k A[m][k]*Bt[n][k] -----------
// m97 structure: 128x128 tile, BK=32, global_load_lds(16B), 16x16x32 f16 MFMA.
// K = N = 1024 compile-time for all four GEMMs in this problem.
template <bool OUT_F32>
__device__ __forceinline__ void gemm_body(const f16* __restrict__ A,
                                          const f16* __restrict__ Bt,
                                          void* __restrict__ Cv,
                                          int rowTile, int colTile) {
    constexpr int K = DMODEL, N = DMODEL;
    __shared__ f16 As[128 * 32];
    __shared__ f16 Bs[128 * 32];
    const int t = threadIdx.x;
    const int lane = t & 63;
    const int w = t >> 6;
    const int wm = w >> 1, wn = w & 1;
    const long rowBase = (long)rowTile * 128;
    const long colBase = (long)colTile * 128;
    const int qrow = lane & 15;
    const int quad = lane >> 4;

    v4f acc[4][4] = {};

    const int srow = w * 32 + (lane >> 2);
    const int scol = (lane & 3) * 8;
    const f16* aptr = A + (rowBase + srow) * (long)K + scol;
    const f16* bptr = Bt + (colBase + srow) * (long)K + scol;
    f16* lA0 = &As[srow * 32 + scol];
    f16* lA1 = &As[(srow + 16) * 32 + scol];
    f16* lB0 = &Bs[srow * 32 + scol];
    f16* lB1 = &Bs[(srow + 16) * 32 + scol];

    for (int k0 = 0; k0 < K; k0 += 32) {
        async_copy16(aptr + k0, lA0);
        async_copy16(aptr + 16 * (long)K + k0, lA1);
        async_copy16(bptr + k0, lB0);
        async_copy16(bptr + 16 * (long)K + k0, lB1);
        __syncthreads();
        f16x8 af[4], bf[4];
#pragma unroll
        for (int mt = 0; mt < 4; ++mt)
            af[mt] = *(const f16x8*)(&As[(wm * 64 + mt * 16 + qrow) * 32 + quad * 8]);
#pragma unroll
        for (int nt = 0; nt < 4; ++nt)
            bf[nt] = *(const f16x8*)(&Bs[(wn * 64 + nt * 16 + qrow) * 32 + quad * 8]);
#pragma unroll
        for (int mt = 0; mt < 4; ++mt)
#pragma unroll
            for (int nt = 0; nt < 4; ++nt)
                acc[mt][nt] = __builtin_amdgcn_mfma_f32_16x16x32_f16(af[mt], bf[nt],
                                                                     acc[mt][nt], 0, 0, 0);
        __syncthreads();
    }

    // C/D layout (m89-verified): row = quad*4 + r, col = lane&15
#pragma unroll
    for (int mt = 0; mt < 4; ++mt)
#pragma unroll
        for (int nt = 0; nt < 4; ++nt) {
            const long col = colBase + wn * 64 + nt * 16 + qrow;
#pragma unroll
            for (int r = 0; r < 4; ++r) {
                const long row = rowBase + wm * 64 + mt * 16 + quad * 4 + r;
                if (OUT_F32)
                    ((float*)Cv)[row * (long)N + col] = acc[mt][nt][r];
                else
                    ((f16*)Cv)[row * (long)N + col] = (f16)acc[mt][nt][r];
            }
        }
}

// Fused Q/K/V projection: grid (8, 128). y<64 -> Q tiles, y<96 -> K, else V.
__global__ __launch_bounds__(256, 2)
void gemm_qkv(const f16* __restrict__ A0, const f16* __restrict__ A1,
              const f16* __restrict__ A2, const f16* __restrict__ B0,
              const f16* __restrict__ B1, const f16* __restrict__ B2,
              f16* __restrict__ C0, f16* __restrict__ C1, f16* __restrict__ C2) {
    int by = blockIdx.y;
    const f16 *A, *Bt;
    f16* C;
    if (by < 64) {
        A = A0; Bt = B0; C = C0;
    } else if (by < 96) {
        A = A1; Bt = B1; C = C1; by -= 64;
    } else {
        A = A2; Bt = B2; C = C2; by -= 96;
    }
    gemm_body<false>(A, Bt, (void*)C, by, blockIdx.x);
}

__global__ __launch_bounds__(256, 2)
void gemm_out(const f16* __restrict__ A, const f16* __restrict__ Bt,
              float* __restrict__ C) {
    gemm_body<true>(A, Bt, (void*)C, blockIdx.y, blockIdx.x);
}

// -------- per-column scores + softmax over the 16 valid query rows ----------
// grid (LKV, B), block 256 = 16 heads x 16 row-offsets j; q = 2*col + j.
// Q rows staged to LDS fully coalesced; 16B h-rotation swizzle keeps LDS
// access at <=2-way bank aliasing (free, m136). K h-segs padded to stride 68.
__global__ __launch_bounds__(256)
void attn_scores(const f16* __restrict__ Q, const f16* __restrict__ Km,
                 float* __restrict__ attnw) {
    const int c = blockIdx.x, b = blockIdx.y;
    const int t = threadIdx.x;
    __shared__ float Ks[16 * 68];     // h-seg stride 68 f32: bank offset h*4
    __shared__ f16 Qs[16 * 1032];     // row stride 1032 f16 (+4 words -> j*4 banks)

    {   // K row: 256 threads x 4 elems, coalesced
        const f16* krow = Km + (size_t)(b * LKV_ + c) * DMODEL;
        f16x4 kv = *(const f16x4*)(krow + t * 4);
#pragma unroll
        for (int u = 0; u < 4; ++u) {
            int g = t * 4 + u;
            Ks[(g >> 6) * 68 + (g & 63)] = (float)kv[u];
        }
    }
    {   // Q rows 2c..2c+15: row j = t>>4; 16 threads/row x 4 iters x 16 f16
        // covers the FULL 1024-elem row (R2 bug: only first 256 were staged)
        const int j = t >> 4, c16 = t & 15;
        int q = 2 * c + j;
        if (q > LQ_ - 1) q = LQ_ - 1;   // clamp staging; masked in score
        const f16* qrow = Q + (size_t)(b * LQ_ + q) * DMODEL;
#pragma unroll
        for (int it = 0; it < 4; ++it) {
            const int Dbase = c16 * 16 + it * 256;
#pragma unroll
            for (int half = 0; half < 2; ++half) {
                f16x8 x = *(const f16x8*)(qrow + Dbase + half * 8);
                const int D = Dbase + half * 8;
                const int h = D >> 6, bb = (D >> 3) & 7;
                *(f16x8*)(&Qs[j * 1032 + h * 64 + ((bb + h) & 7) * 8]) = x;
            }
        }
    }
    __syncthreads();

    const int h = t >> 4, j = t & 15;
    const int q = STRIDE * c + j;
    float a = 0.f;
#pragma unroll
    for (int bb = 0; bb < 8; ++bb) {
        f16x8 qv = *(const f16x8*)(&Qs[j * 1032 + h * 64 + ((bb + h) & 7) * 8]);
#pragma unroll
        for (int u = 0; u < 8; ++u)
            a += (float)qv[u] * Ks[h * 68 + bb * 8 + u];
    }
    float s = (q < LQ_) ? a : -1e30f;
    // softmax over j: 16 contiguous lanes share h (xor<16 stays in group)
    float m = s;
#pragma unroll
    for (int o = 1; o < 16; o <<= 1) m = fmaxf(m, __shfl_xor(m, o, 64));
    float p = (q < LQ_) ? __expf(s - m) : 0.f;
    float sum = p;
#pragma unroll
    for (int o = 1; o < 16; o <<= 1) sum += __shfl_xor(sum, o, 64);
    attnw[(size_t)((b * LKV_ + c) * NH + h) * SPAN + j] = p / sum;
}

// ---- ctx[b,q,h,:] = sum_i attn[b, q/2-i, h, (q&1)+2i] * V[b, q/2-i, h, :] ----
// grid (LQ, B), block 256 = 4 head-groups x 64 dims; each thread does 4 heads
__global__ __launch_bounds__(256)
void ctx_gather(const float* __restrict__ attnw, const f16* __restrict__ V,
                f16* __restrict__ ctx) {
    const int qi = blockIdx.x, b = blockIdx.y;
    const int t = threadIdx.x;
    const int d = t & 63;
    const int hg = t >> 6;
    const int kmax = qi >> 1;
    const int j0 = qi & 1;
    float acc[4] = {0.f, 0.f, 0.f, 0.f};
#pragma unroll
    for (int i = 0; i < SPAN / STRIDE; ++i) {
        const int k = kmax - i;
        if (k < 0) break;
        const int j = j0 + STRIDE * i;
        const float* arow = attnw + (size_t)(b * LKV_ + k) * (NH * SPAN);
        const f16* vrow = V + (size_t)(b * LKV_ + k) * DMODEL;
#pragma unroll
        for (int hh = 0; hh < 4; ++hh) {
            const int h = hg * 4 + hh;
            acc[hh] += arow[h * SPAN + j] * (float)vrow[h * HD + d];
        }
    }
    f16* crow = ctx + (size_t)(b * LQ_ + qi) * DMODEL;
#pragma unroll
    for (int hh = 0; hh < 4; ++hh) {
        const int h = hg * 4 + hh;
        crow[h * HD + d] = (f16)acc[hh];
    }
}

// ---------------------------------------------------------------------------
extern "C" void kernel_launch(void* const* d_in, const int* in_sizes, int n_in,
                              void* d_out, int out_size, void* d_ws, size_t ws_size,
                              hipStream_t stream) {
    const float* q  = (const float*)d_in[0];
    const float* k  = (const float*)d_in[1];
    const float* v  = (const float*)d_in[2];
    const float* Wq = (const float*)d_in[3];
    const float* Wk = (const float*)d_in[4];
    const float* Wv = (const float*)d_in[5];
    const float* Wo = (const float*)d_in[6];
    // d_in[7]=span(16), d_in[8]=stride(2): fixed by setup_inputs, hard-coded.
    float* out = (float*)d_out;

    const size_t NW = (size_t)DMODEL * DMODEL;

    char* p = (char*)d_ws;
    f16* qh  = (f16*)p; p += NQ_ELEMS * 2;
    f16* kh  = (f16*)p; p += NKV_ELEMS * 2;
    f16* vh  = (f16*)p; p += NKV_ELEMS * 2;
    f16* WqT = (f16*)p; p += NW * 2;
    f16* WkT = (f16*)p; p += NW * 2;
    f16* WvT = (f16*)p; p += NW * 2;
    f16* WoT = (f16*)p; p += NW * 2;
    f16* Qh  = (f16*)p; p += NQ_ELEMS * 2;
    f16* Kh  = (f16*)p; p += NKV_ELEMS * 2;
    f16* Vh  = (f16*)p; p += NKV_ELEMS * 2;
    float* attnw = (float*)p; p += (size_t)B_ * LKV_ * NH * SPAN * 4;
    f16* ctxh = (f16*)p; p += NQ_ELEMS * 2;

    // 1) all f32->f16 input converts in one launch (16384 blocks)
    const size_t total_vec4 = (NQ_ELEMS + 2 * NKV_ELEMS) / 4;
    cvt_all<<<dim3((unsigned)(total_vec4 / 256)), 256, 0, stream>>>(q, k, v, qh, kh, vh);

    // 2) all 4 weight transposes in one launch
    transpose_all<<<dim3(16, 16, 4), dim3(64, 4), 0, stream>>>(
        Wq, Wk, Wv, Wo, WqT, WkT, WvT, WoT);

    // 3) Q/K/V projections fused: 1024 blocks (4 blocks/CU)
    gemm_qkv<<<dim3(8, 128), 256, 0, stream>>>(qh, kh, vh, WqT, WkT, WvT, Qh, Kh, Vh);

    // 4) per-column masked scores + query-axis softmax
    attn_scores<<<dim3(LKV_, B_), 256, 0, stream>>>(Qh, Kh, attnw);

    // 5) per-query gather of weighted V
    ctx_gather<<<dim3(LQ_, B_), 256, 0, stream>>>(attnw, Vh, ctxh);

    // 6) output projection (f32 out)
    gemm_out<<<dim3(8, 64), 256, 0, stream>>>(ctxh, WoT, out);
}

// Round 4
// 241.720 us; speedup vs baseline: 1.2941x; 1.1045x over previous
//
#include <hip/hip_runtime.h>
#include <cstdint>
#include <cstddef>

// ---------------------------------------------------------------------------
// SparseMHADecoder: B=2, LQ=4096, LKV=2048, D=1024, H=16, d=64, span=16, stride=2
// R4: (a) attn_scores 4 cols/block (Q staged once: 139->48MB traffic),
//     (b) ctx_gather 16 queries/block (V staged once: 134->16MB),
//     (c) XCD swizzle in GEMMs (A-panel L2 locality: FETCH 134->~70MB),
//     (d) cvt+transpose fused into one launch. 5 launches total.
// fp16 numerics kept (absmax 0.0156 vs 0.084 threshold).
// ---------------------------------------------------------------------------

typedef _Float16 f16;
typedef _Float16 f16x4 __attribute__((ext_vector_type(4)));
typedef _Float16 f16x8 __attribute__((ext_vector_type(8)));
typedef float v4f __attribute__((ext_vector_type(4)));

#define B_  2
#define LQ_ 4096
#define LKV_ 2048
#define DMODEL 1024
#define NH 16
#define HD 64
#define SPAN 16
#define STRIDE 2

#define NQ_ELEMS  ((size_t)B_ * LQ_ * DMODEL)   // 8388608
#define NKV_ELEMS ((size_t)B_ * LKV_ * DMODEL)  // 4194304

__device__ __forceinline__ void async_copy16(const f16* g, f16* l) {
    __builtin_amdgcn_global_load_lds((const __attribute__((address_space(1))) void*)g,
                                     (__attribute__((address_space(3))) void*)l, 16, 0, 0);
}

// ------- fused prep: f32->f16 convert of q,k,v + 4 weight transposes --------
// blocks [0,16384): cvt;  [16384, 17408): transpose (decoded 16x16x4 tiles)
__global__ __launch_bounds__(256)
void prep_all(const float* __restrict__ q, const float* __restrict__ k,
              const float* __restrict__ v, f16* __restrict__ qh,
              f16* __restrict__ kh, f16* __restrict__ vh,
              const float* __restrict__ W0, const float* __restrict__ W1,
              const float* __restrict__ W2, const float* __restrict__ W3,
              f16* __restrict__ T0, f16* __restrict__ T1,
              f16* __restrict__ T2, f16* __restrict__ T3) {
    const int t = threadIdx.x;
    if (blockIdx.x < 16384) {
        size_t i = ((size_t)blockIdx.x * 256 + t) * 4;
        const float* src;
        f16* dst;
        if (i < NQ_ELEMS) {
            src = q + i; dst = qh + i;
        } else if (i < NQ_ELEMS + NKV_ELEMS) {
            src = k + (i - NQ_ELEMS); dst = kh + (i - NQ_ELEMS);
        } else {
            src = v + (i - NQ_ELEMS - NKV_ELEMS); dst = vh + (i - NQ_ELEMS - NKV_ELEMS);
        }
        float4 x = *(const float4*)src;
        f16x4 o = {(f16)x.x, (f16)x.y, (f16)x.z, (f16)x.w};
        *(f16x4*)dst = o;
    } else {
        const int bid = blockIdx.x - 16384;
        const int z = bid >> 8, rem = bid & 255;
        const int bx = rem & 15, byy = rem >> 4;
        const float* W;
        f16* Wt;
        switch (z) {
            case 0: W = W0; Wt = T0; break;
            case 1: W = W1; Wt = T1; break;
            case 2: W = W2; Wt = T2; break;
            default: W = W3; Wt = T3; break;
        }
        __shared__ float tile[64][65];
        const int r0 = byy * 64, c0 = bx * 64;
        const int tx = t & 63, ty = t >> 6;  // (64,4)
        for (int i = ty; i < 64; i += 4)
            tile[i][tx] = W[(long)(r0 + i) * DMODEL + c0 + tx];
        __syncthreads();
        for (int i = ty; i < 64; i += 4)
            Wt[(long)(c0 + i) * DMODEL + r0 + tx] = (f16)tile[tx][i];
    }
}

// ---------------- fp16 GEMM body, C[m][n] = sum_k A[m][k]*Bt[n][k] -----------
// m97 structure: 128x128 tile, BK=32, global_load_lds(16B), 16x16x32 f16 MFMA.
template <bool OUT_F32>
__device__ __forceinline__ void gemm_body(const f16* __restrict__ A,
                                          const f16* __restrict__ Bt,
                                          void* __restrict__ Cv,
                                          int rowTile, int colTile) {
    constexpr int K = DMODEL, N = DMODEL;
    __shared__ f16 As[128 * 32];
    __shared__ f16 Bs[128 * 32];
    const int t = threadIdx.x;
    const int lane = t & 63;
    const int w = t >> 6;
    const int wm = w >> 1, wn = w & 1;
    const long rowBase = (long)rowTile * 128;
    const long colBase = (long)colTile * 128;
    const int qrow = lane & 15;
    const int quad = lane >> 4;

    v4f acc[4][4] = {};

    const int srow = w * 32 + (lane >> 2);
    const int scol = (lane & 3) * 8;
    const f16* aptr = A + (rowBase + srow) * (long)K + scol;
    const f16* bptr = Bt + (colBase + srow) * (long)K + scol;
    f16* lA0 = &As[srow * 32 + scol];
    f16* lA1 = &As[(srow + 16) * 32 + scol];
    f16* lB0 = &Bs[srow * 32 + scol];
    f16* lB1 = &Bs[(srow + 16) * 32 + scol];

    for (int k0 = 0; k0 < K; k0 += 32) {
        async_copy16(aptr + k0, lA0);
        async_copy16(aptr + 16 * (long)K + k0, lA1);
        async_copy16(bptr + k0, lB0);
        async_copy16(bptr + 16 * (long)K + k0, lB1);
        __syncthreads();
        f16x8 af[4], bf[4];
#pragma unroll
        for (int mt = 0; mt < 4; ++mt)
            af[mt] = *(const f16x8*)(&As[(wm * 64 + mt * 16 + qrow) * 32 + quad * 8]);
#pragma unroll
        for (int nt = 0; nt < 4; ++nt)
            bf[nt] = *(const f16x8*)(&Bs[(wn * 64 + nt * 16 + qrow) * 32 + quad * 8]);
#pragma unroll
        for (int mt = 0; mt < 4; ++mt)
#pragma unroll
            for (int nt = 0; nt < 4; ++nt)
                acc[mt][nt] = __builtin_amdgcn_mfma_f32_16x16x32_f16(af[mt], bf[nt],
                                                                     acc[mt][nt], 0, 0, 0);
        __syncthreads();
    }

    // C/D layout (m89-verified): row = quad*4 + r, col = lane&15
#pragma unroll
    for (int mt = 0; mt < 4; ++mt)
#pragma unroll
        for (int nt = 0; nt < 4; ++nt) {
            const long col = colBase + wn * 64 + nt * 16 + qrow;
#pragma unroll
            for (int r = 0; r < 4; ++r) {
                const long row = rowBase + wm * 64 + mt * 16 + quad * 4 + r;
                if (OUT_F32)
                    ((float*)Cv)[row * (long)N + col] = acc[mt][nt][r];
                else
                    ((f16*)Cv)[row * (long)N + col] = (f16)acc[mt][nt][r];
            }
        }
}

// Fused Q/K/V projection, 1024 blocks, XCD-swizzled:
// xcd = id&7 (presumed round-robin); within an XCD, col-tile cycles fastest
// so the A row-panel's 8 col-tiles are co-XCD with reuse distance 1.
__global__ __launch_bounds__(256, 2)
void gemm_qkv(const f16* __restrict__ A0, const f16* __restrict__ A1,
              const f16* __restrict__ A2, const f16* __restrict__ B0,
              const f16* __restrict__ B1, const f16* __restrict__ B2,
              f16* __restrict__ C0, f16* __restrict__ C1, f16* __restrict__ C2) {
    const int id = blockIdx.x;
    const int xcd = id & 7;
    const int g = id >> 3;            // 0..127
    const int ct = g & 7;             // col tile
    int rowIdx = (g >> 3) + xcd * 16; // 0..127, each XCD owns 16 row-panels
    const f16 *A, *Bt;
    f16* C;
    if (rowIdx < 64) {
        A = A0; Bt = B0; C = C0;
    } else if (rowIdx < 96) {
        A = A1; Bt = B1; C = C1; rowIdx -= 64;
    } else {
        A = A2; Bt = B2; C = C2; rowIdx -= 96;
    }
    gemm_body<false>(A, Bt, (void*)C, rowIdx, ct);
}

__global__ __launch_bounds__(256, 2)
void gemm_out(const f16* __restrict__ A, const f16* __restrict__ Bt,
              float* __restrict__ C) {
    const int id = blockIdx.x;        // 512 blocks
    const int xcd = id & 7;
    const int g = id >> 3;            // 0..63
    const int ct = g & 7;
    const int rowIdx = (g >> 3) + xcd * 8;  // 0..63
    gemm_body<true>(A, Bt, (void*)C, rowIdx, ct);
}

// -------- per-column scores + softmax over the 16 valid query rows ----------
// grid (LKV/4, B), block 256 = 16 heads x 16 j. Each block does 4 columns,
// staging the 22 shared Q rows once (4.3x less Q traffic than 1 col/block).
// Row-stride 1032 f16 => row r rotates banks by 4 words; j/j+8 alias = 2-way
// (free, m136). 16B h-rotation swizzle keeps the h*64 offsets conflict-free.
__global__ __launch_bounds__(256)
void attn_scores(const f16* __restrict__ Q, const f16* __restrict__ Km,
                 float* __restrict__ attnw) {
    const int c0 = blockIdx.x * 4, b = blockIdx.y;
    const int t = threadIdx.x;
    __shared__ f16 Qs[24 * 1032];   // rows 0..21 used; 49.5 KB
    __shared__ f16 Ks[4 * 1032];    // 8.25 KB

    // stage Q rows 2c0 .. 2c0+23 (clamped), fully coalesced 16B chunks
#pragma unroll
    for (int it = 0; it < 12; ++it) {
        const int ch = t + 256 * it;        // 24 rows x 128 chunks
        const int row = ch >> 7, off = (ch & 127) * 8;
        int qq = 2 * c0 + row;
        if (qq > LQ_ - 1) qq = LQ_ - 1;     // clamp staging; masked in score
        f16x8 x = *(const f16x8*)(Q + (size_t)(b * LQ_ + qq) * DMODEL + off);
        const int h = off >> 6, bb = (off >> 3) & 7;
        *(f16x8*)(&Qs[row * 1032 + h * 64 + ((bb + h) & 7) * 8]) = x;
    }
    // stage K rows c0..c0+3
#pragma unroll
    for (int it = 0; it < 2; ++it) {
        const int ch = t + 256 * it;        // 4 rows x 128 chunks
        const int row = ch >> 7, off = (ch & 127) * 8;
        f16x8 x = *(const f16x8*)(Km + (size_t)(b * LKV_ + c0 + row) * DMODEL + off);
        const int h = off >> 6, bb = (off >> 3) & 7;
        *(f16x8*)(&Ks[row * 1032 + h * 64 + ((bb + h) & 7) * 8]) = x;
    }
    __syncthreads();

    const int h = t >> 4, j = t & 15;
#pragma unroll
    for (int ci = 0; ci < 4; ++ci) {
        const int c = c0 + ci;
        const int q = STRIDE * c + j;
        const int row = 2 * ci + j;
        float a = 0.f;
#pragma unroll
        for (int bb = 0; bb < 8; ++bb) {
            const int off = h * 64 + ((bb + h) & 7) * 8;
            f16x8 qv = *(const f16x8*)(&Qs[row * 1032 + off]);
            f16x8 kv = *(const f16x8*)(&Ks[ci * 1032 + off]);  // wave-broadcast
#pragma unroll
            for (int u = 0; u < 8; ++u) a += (float)qv[u] * (float)kv[u];
        }
        float s = (q < LQ_) ? a : -1e30f;
        float m = s;
#pragma unroll
        for (int o = 1; o < 16; o <<= 1) m = fmaxf(m, __shfl_xor(m, o, 64));
        float p = (q < LQ_) ? __expf(s - m) : 0.f;
        float sum = p;
#pragma unroll
        for (int o = 1; o < 16; o <<= 1) sum += __shfl_xor(sum, o, 64);
        attnw[(size_t)((b * LKV_ + c) * NH + h) * SPAN + j] = p / sum;
    }
}

// ---- ctx[b,q,h,:] = sum_i attn[b, q/2-i, h, (q&1)+2i] * V[b, q/2-i, h, :] ----
// grid (LQ/16, B), block 256 = 4 head-groups x 64 dims. Each block does 16
// queries, staging the 15 shared V rows + attn rows once (8x less V traffic).
__global__ __launch_bounds__(256)
void ctx_gather(const float* __restrict__ attnw, const f16* __restrict__ V,
                f16* __restrict__ ctx) {
    const int q0 = blockIdx.x * 16, b = blockIdx.y;
    const int t = threadIdx.x;
    const int kbase = (q0 >> 1) - 7;
    __shared__ f16 Vs[16 * 1024];     // 32 KB, rows kbase..kbase+15 (clamped)
    __shared__ float A_lds[16 * 256]; // 16 KB

    // stage V rows (coalesced 16B chunks)
#pragma unroll
    for (int it = 0; it < 8; ++it) {
        const int ch = t + 256 * it;       // 16 rows x 128 chunks
        const int row = ch >> 7, off = (ch & 127) * 8;
        int k = kbase + row;
        k = (k < 0) ? 0 : ((k > LKV_ - 1) ? LKV_ - 1 : k);
        *(f16x8*)(&Vs[row * 1024 + off]) =
            *(const f16x8*)(V + (size_t)(b * LKV_ + k) * DMODEL + off);
    }
    // stage attn rows (256 f32 per k-row)
#pragma unroll
    for (int it = 0; it < 4; ++it) {
        const int ch = t + 256 * it;       // 16 rows x 64 chunks of 4 f32
        const int row = ch >> 6, off = (ch & 63) * 4;
        int k = kbase + row;
        k = (k < 0) ? 0 : ((k > LKV_ - 1) ? LKV_ - 1 : k);
        *(float4*)(&A_lds[row * 256 + off]) =
            *(const float4*)(attnw + (size_t)(b * LKV_ + k) * 256 + off);
    }
    __syncthreads();

    const int d = t & 63;
    const int hg = t >> 6;
#pragma unroll
    for (int ql = 0; ql < 16; ++ql) {
        const int q = q0 + ql;
        const int j0 = q & 1;
        float acc[4] = {0.f, 0.f, 0.f, 0.f};
#pragma unroll
        for (int i = 0; i < SPAN / STRIDE; ++i) {
            const int kq = (q >> 1) - i;
            if (kq < 0) break;
            const int rr = kq - kbase;     // (ql>>1)+7-i in [0,14]
#pragma unroll
            for (int hh = 0; hh < 4; ++hh) {
                const int h = hg * 4 + hh;
                acc[hh] += A_lds[rr * 256 + h * 16 + j0 + 2 * i] *  // broadcast
                           (float)Vs[rr * 1024 + h * 64 + d];       // 2-way
            }
        }
        f16* crow = ctx + (size_t)(b * LQ_ + q) * DMODEL;
#pragma unroll
        for (int hh = 0; hh < 4; ++hh) {
            const int h = hg * 4 + hh;
            crow[h * HD + d] = (f16)acc[hh];
        }
    }
}

// ---------------------------------------------------------------------------
extern "C" void kernel_launch(void* const* d_in, const int* in_sizes, int n_in,
                              void* d_out, int out_size, void* d_ws, size_t ws_size,
                              hipStream_t stream) {
    const float* q  = (const float*)d_in[0];
    const float* k  = (const float*)d_in[1];
    const float* v  = (const float*)d_in[2];
    const float* Wq = (const float*)d_in[3];
    const float* Wk = (const float*)d_in[4];
    const float* Wv = (const float*)d_in[5];
    const float* Wo = (const float*)d_in[6];
    // d_in[7]=span(16), d_in[8]=stride(2): fixed by setup_inputs, hard-coded.
    float* out = (float*)d_out;

    const size_t NW = (size_t)DMODEL * DMODEL;

    char* p = (char*)d_ws;
    f16* qh  = (f16*)p; p += NQ_ELEMS * 2;
    f16* kh  = (f16*)p; p += NKV_ELEMS * 2;
    f16* vh  = (f16*)p; p += NKV_ELEMS * 2;
    f16* WqT = (f16*)p; p += NW * 2;
    f16* WkT = (f16*)p; p += NW * 2;
    f16* WvT = (f16*)p; p += NW * 2;
    f16* WoT = (f16*)p; p += NW * 2;
    f16* Qh  = (f16*)p; p += NQ_ELEMS * 2;
    f16* Kh  = (f16*)p; p += NKV_ELEMS * 2;
    f16* Vh  = (f16*)p; p += NKV_ELEMS * 2;
    float* attnw = (float*)p; p += (size_t)B_ * LKV_ * NH * SPAN * 4;
    f16* ctxh = (f16*)p; p += NQ_ELEMS * 2;

    // 1) fused converts + weight transposes (16384 + 1024 blocks)
    prep_all<<<dim3(17408), 256, 0, stream>>>(q, k, v, qh, kh, vh,
                                              Wq, Wk, Wv, Wo, WqT, WkT, WvT, WoT);

    // 2) Q/K/V projections fused, XCD-swizzled (1024 blocks)
    gemm_qkv<<<dim3(1024), 256, 0, stream>>>(qh, kh, vh, WqT, WkT, WvT, Qh, Kh, Vh);

    // 3) per-column masked scores + query-axis softmax (4 cols/block)
    attn_scores<<<dim3(LKV_ / 4, B_), 256, 0, stream>>>(Qh, Kh, attnw);

    // 4) per-query gather of weighted V (16 queries/block)
    ctx_gather<<<dim3(LQ_ / 16, B_), 256, 0, stream>>>(attnw, Vh, ctxh);

    // 5) output projection (f32 out), XCD-swizzled (512 blocks)
    gemm_out<<<dim3(512), 256, 0, stream>>>(ctxh, WoT, out);
}

// Round 5
// 229.293 us; speedup vs baseline: 1.3642x; 1.0542x over previous
//
#include <hip/hip_runtime.h>
#include <cstdint>
#include <cstddef>

// ---------------------------------------------------------------------------
// SparseMHADecoder: B=2, LQ=4096, LKV=2048, D=1024, H=16, d=64, span=16, stride=2
// R5: GEMM K-loop restructure: BK=64 (half the barriers vs BK=32) + XOR
//     chunk-swizzle in LDS staging (bank-conflict-free ds_read_b128 while
//     keeping global_load_lds's wave-uniform-base+lane*16 constraint).
//     R4 counters: gemm_qkv MfmaUtil 29%, 4.2M LDS conflict-cycles, HBM 16%.
// Attn path / prep unchanged from R4 (so their true cost surfaces in top-5).
// ---------------------------------------------------------------------------

typedef _Float16 f16;
typedef _Float16 f16x4 __attribute__((ext_vector_type(4)));
typedef _Float16 f16x8 __attribute__((ext_vector_type(8)));
typedef float v4f __attribute__((ext_vector_type(4)));

#define B_  2
#define LQ_ 4096
#define LKV_ 2048
#define DMODEL 1024
#define NH 16
#define HD 64
#define SPAN 16
#define STRIDE 2

#define NQ_ELEMS  ((size_t)B_ * LQ_ * DMODEL)   // 8388608
#define NKV_ELEMS ((size_t)B_ * LKV_ * DMODEL)  // 4194304

__device__ __forceinline__ void async_copy16(const f16* g, f16* l) {
    __builtin_amdgcn_global_load_lds((const __attribute__((address_space(1))) void*)g,
                                     (__attribute__((address_space(3))) void*)l, 16, 0, 0);
}

// ------- fused prep: f32->f16 convert of q,k,v + 4 weight transposes --------
__global__ __launch_bounds__(256)
void prep_all(const float* __restrict__ q, const float* __restrict__ k,
              const float* __restrict__ v, f16* __restrict__ qh,
              f16* __restrict__ kh, f16* __restrict__ vh,
              const float* __restrict__ W0, const float* __restrict__ W1,
              const float* __restrict__ W2, const float* __restrict__ W3,
              f16* __restrict__ T0, f16* __restrict__ T1,
              f16* __restrict__ T2, f16* __restrict__ T3) {
    const int t = threadIdx.x;
    if (blockIdx.x < 16384) {
        size_t i = ((size_t)blockIdx.x * 256 + t) * 4;
        const float* src;
        f16* dst;
        if (i < NQ_ELEMS) {
            src = q + i; dst = qh + i;
        } else if (i < NQ_ELEMS + NKV_ELEMS) {
            src = k + (i - NQ_ELEMS); dst = kh + (i - NQ_ELEMS);
        } else {
            src = v + (i - NQ_ELEMS - NKV_ELEMS); dst = vh + (i - NQ_ELEMS - NKV_ELEMS);
        }
        float4 x = *(const float4*)src;
        f16x4 o = {(f16)x.x, (f16)x.y, (f16)x.z, (f16)x.w};
        *(f16x4*)dst = o;
    } else {
        const int bid = blockIdx.x - 16384;
        const int z = bid >> 8, rem = bid & 255;
        const int bx = rem & 15, byy = rem >> 4;
        const float* W;
        f16* Wt;
        switch (z) {
            case 0: W = W0; Wt = T0; break;
            case 1: W = W1; Wt = T1; break;
            case 2: W = W2; Wt = T2; break;
            default: W = W3; Wt = T3; break;
        }
        __shared__ float tile[64][65];
        const int r0 = byy * 64, c0 = bx * 64;
        const int tx = t & 63, ty = t >> 6;  // (64,4)
        for (int i = ty; i < 64; i += 4)
            tile[i][tx] = W[(long)(r0 + i) * DMODEL + c0 + tx];
        __syncthreads();
        for (int i = ty; i < 64; i += 4)
            Wt[(long)(c0 + i) * DMODEL + r0 + tx] = (f16)tile[tx][i];
    }
}

// ---------------- fp16 GEMM body, C[m][n] = sum_k A[m][k]*Bt[n][k] -----------
// 128x128 tile, BK=64, global_load_lds(16B) with XOR chunk swizzle:
// LDS position p (16B chunks, 8/row) of row r holds global chunk p^(r&7).
// ds_read_b128 then covers all 8 bank-groups 2x per phase (2-way = free).
template <bool OUT_F32>
__device__ __forceinline__ void gemm_body(const f16* __restrict__ A,
                                          const f16* __restrict__ Bt,
                                          void* __restrict__ Cv,
                                          int rowTile, int colTile) {
    constexpr int K = DMODEL, N = DMODEL;
    __shared__ f16 As[128 * 64];
    __shared__ f16 Bs[128 * 64];
    const int t = threadIdx.x;
    const int lane = t & 63;
    const int w = t >> 6;
    const int wm = w >> 1, wn = w & 1;
    const long rowBase = (long)rowTile * 128;
    const long colBase = (long)colTile * 128;
    const int qrow = lane & 15;
    const int quad = lane >> 4;

    v4f acc[4][4] = {};

    // staging: thread t covers rows srow+32i (i=0..3), LDS chunk schunk;
    // fetches global chunk schunk^(srow&7)  (i*32 = 0 mod 8 -> same xor)
    const int srow = t >> 3;          // 0..31
    const int schunk = t & 7;
    const int gchunk = schunk ^ (srow & 7);
    const f16* aptr = A + (rowBase + srow) * (long)K + gchunk * 8;
    const f16* bptr = Bt + (colBase + srow) * (long)K + gchunk * 8;
    f16* lA = &As[srow * 64 + schunk * 8];
    f16* lB = &Bs[srow * 64 + schunk * 8];

    for (int k0 = 0; k0 < K; k0 += 64) {
#pragma unroll
        for (int i = 0; i < 4; ++i) {
            async_copy16(aptr + k0 + i * 32 * (long)K, lA + i * 2048);
            async_copy16(bptr + k0 + i * 32 * (long)K, lB + i * 2048);
        }
        __syncthreads();  // drains vmcnt(0): staged tile visible
#pragma unroll
        for (int s = 0; s < 2; ++s) {   // two K=32 MFMA steps per BK=64 tile
            const int xk = (s * 4 + quad) ^ (qrow & 7);  // swizzled chunk
            f16x8 af[4], bf[4];
#pragma unroll
            for (int mt = 0; mt < 4; ++mt)
                af[mt] = *(const f16x8*)(&As[(wm * 64 + mt * 16 + qrow) * 64 + xk * 8]);
#pragma unroll
            for (int nt = 0; nt < 4; ++nt)
                bf[nt] = *(const f16x8*)(&Bs[(wn * 64 + nt * 16 + qrow) * 64 + xk * 8]);
#pragma unroll
            for (int mt = 0; mt < 4; ++mt)
#pragma unroll
                for (int nt = 0; nt < 4; ++nt)
                    acc[mt][nt] = __builtin_amdgcn_mfma_f32_16x16x32_f16(
                        af[mt], bf[nt], acc[mt][nt], 0, 0, 0);
        }
        __syncthreads();  // all reads done before next stage overwrites
    }

    // C/D layout (m89-verified): row = quad*4 + r, col = lane&15
#pragma unroll
    for (int mt = 0; mt < 4; ++mt)
#pragma unroll
        for (int nt = 0; nt < 4; ++nt) {
            const long col = colBase + wn * 64 + nt * 16 + qrow;
#pragma unroll
            for (int r = 0; r < 4; ++r) {
                const long row = rowBase + wm * 64 + mt * 16 + quad * 4 + r;
                if (OUT_F32)
                    ((float*)Cv)[row * (long)N + col] = acc[mt][nt][r];
                else
                    ((f16*)Cv)[row * (long)N + col] = (f16)acc[mt][nt][r];
            }
        }
}

// Fused Q/K/V projection, 1024 blocks, XCD-swizzled (R4-verified: FETCH -82%).
__global__ __launch_bounds__(256, 2)
void gemm_qkv(const f16* __restrict__ A0, const f16* __restrict__ A1,
              const f16* __restrict__ A2, const f16* __restrict__ B0,
              const f16* __restrict__ B1, const f16* __restrict__ B2,
              f16* __restrict__ C0, f16* __restrict__ C1, f16* __restrict__ C2) {
    const int id = blockIdx.x;
    const int xcd = id & 7;
    const int g = id >> 3;            // 0..127
    const int ct = g & 7;             // col tile
    int rowIdx = (g >> 3) + xcd * 16; // 0..127
    const f16 *A, *Bt;
    f16* C;
    if (rowIdx < 64) {
        A = A0; Bt = B0; C = C0;
    } else if (rowIdx < 96) {
        A = A1; Bt = B1; C = C1; rowIdx -= 64;
    } else {
        A = A2; Bt = B2; C = C2; rowIdx -= 96;
    }
    gemm_body<false>(A, Bt, (void*)C, rowIdx, ct);
}

__global__ __launch_bounds__(256, 2)
void gemm_out(const f16* __restrict__ A, const f16* __restrict__ Bt,
              float* __restrict__ C) {
    const int id = blockIdx.x;        // 512 blocks
    const int xcd = id & 7;
    const int g = id >> 3;            // 0..63
    const int ct = g & 7;
    const int rowIdx = (g >> 3) + xcd * 8;  // 0..63
    gemm_body<true>(A, Bt, (void*)C, rowIdx, ct);
}

// -------- per-column scores + softmax over the 16 valid query rows ----------
__global__ __launch_bounds__(256)
void attn_scores(const f16* __restrict__ Q, const f16* __restrict__ Km,
                 float* __restrict__ attnw) {
    const int c0 = blockIdx.x * 4, b = blockIdx.y;
    const int t = threadIdx.x;
    __shared__ f16 Qs[24 * 1032];   // rows 0..21 used; 49.5 KB
    __shared__ f16 Ks[4 * 1032];    // 8.25 KB

#pragma unroll
    for (int it = 0; it < 12; ++it) {
        const int ch = t + 256 * it;        // 24 rows x 128 chunks
        const int row = ch >> 7, off = (ch & 127) * 8;
        int qq = 2 * c0 + row;
        if (qq > LQ_ - 1) qq = LQ_ - 1;     // clamp staging; masked in score
        f16x8 x = *(const f16x8*)(Q + (size_t)(b * LQ_ + qq) * DMODEL + off);
        const int h = off >> 6, bb = (off >> 3) & 7;
        *(f16x8*)(&Qs[row * 1032 + h * 64 + ((bb + h) & 7) * 8]) = x;
    }
#pragma unroll
    for (int it = 0; it < 2; ++it) {
        const int ch = t + 256 * it;        // 4 rows x 128 chunks
        const int row = ch >> 7, off = (ch & 127) * 8;
        f16x8 x = *(const f16x8*)(Km + (size_t)(b * LKV_ + c0 + row) * DMODEL + off);
        const int h = off >> 6, bb = (off >> 3) & 7;
        *(f16x8*)(&Ks[row * 1032 + h * 64 + ((bb + h) & 7) * 8]) = x;
    }
    __syncthreads();

    const int h = t >> 4, j = t & 15;
#pragma unroll
    for (int ci = 0; ci < 4; ++ci) {
        const int c = c0 + ci;
        const int q = STRIDE * c + j;
        const int row = 2 * ci + j;
        float a = 0.f;
#pragma unroll
        for (int bb = 0; bb < 8; ++bb) {
            const int off = h * 64 + ((bb + h) & 7) * 8;
            f16x8 qv = *(const f16x8*)(&Qs[row * 1032 + off]);
            f16x8 kv = *(const f16x8*)(&Ks[ci * 1032 + off]);  // wave-broadcast
#pragma unroll
            for (int u = 0; u < 8; ++u) a += (float)qv[u] * (float)kv[u];
        }
        float s = (q < LQ_) ? a : -1e30f;
        float m = s;
#pragma unroll
        for (int o = 1; o < 16; o <<= 1) m = fmaxf(m, __shfl_xor(m, o, 64));
        float p = (q < LQ_) ? __expf(s - m) : 0.f;
        float sum = p;
#pragma unroll
        for (int o = 1; o < 16; o <<= 1) sum += __shfl_xor(sum, o, 64);
        attnw[(size_t)((b * LKV_ + c) * NH + h) * SPAN + j] = p / sum;
    }
}

// ---- ctx[b,q,h,:] = sum_i attn[b, q/2-i, h, (q&1)+2i] * V[b, q/2-i, h, :] ----
__global__ __launch_bounds__(256)
void ctx_gather(const float* __restrict__ attnw, const f16* __restrict__ V,
                f16* __restrict__ ctx) {
    const int q0 = blockIdx.x * 16, b = blockIdx.y;
    const int t = threadIdx.x;
    const int kbase = (q0 >> 1) - 7;
    __shared__ f16 Vs[16 * 1024];     // 32 KB
    __shared__ float A_lds[16 * 256]; // 16 KB

#pragma unroll
    for (int it = 0; it < 8; ++it) {
        const int ch = t + 256 * it;       // 16 rows x 128 chunks
        const int row = ch >> 7, off = (ch & 127) * 8;
        int k = kbase + row;
        k = (k < 0) ? 0 : ((k > LKV_ - 1) ? LKV_ - 1 : k);
        *(f16x8*)(&Vs[row * 1024 + off]) =
            *(const f16x8*)(V + (size_t)(b * LKV_ + k) * DMODEL + off);
    }
#pragma unroll
    for (int it = 0; it < 4; ++it) {
        const int ch = t + 256 * it;       // 16 rows x 64 chunks of 4 f32
        const int row = ch >> 6, off = (ch & 63) * 4;
        int k = kbase + row;
        k = (k < 0) ? 0 : ((k > LKV_ - 1) ? LKV_ - 1 : k);
        *(float4*)(&A_lds[row * 256 + off]) =
            *(const float4*)(attnw + (size_t)(b * LKV_ + k) * 256 + off);
    }
    __syncthreads();

    const int d = t & 63;
    const int hg = t >> 6;
#pragma unroll
    for (int ql = 0; ql < 16; ++ql) {
        const int q = q0 + ql;
        const int j0 = q & 1;
        float acc[4] = {0.f, 0.f, 0.f, 0.f};
#pragma unroll
        for (int i = 0; i < SPAN / STRIDE; ++i) {
            const int kq = (q >> 1) - i;
            if (kq < 0) break;
            const int rr = kq - kbase;
#pragma unroll
            for (int hh = 0; hh < 4; ++hh) {
                const int h = hg * 4 + hh;
                acc[hh] += A_lds[rr * 256 + h * 16 + j0 + 2 * i] *
                           (float)Vs[rr * 1024 + h * 64 + d];
            }
        }
        f16* crow = ctx + (size_t)(b * LQ_ + q) * DMODEL;
#pragma unroll
        for (int hh = 0; hh < 4; ++hh) {
            const int h = hg * 4 + hh;
            crow[h * HD + d] = (f16)acc[hh];
        }
    }
}

// ---------------------------------------------------------------------------
extern "C" void kernel_launch(void* const* d_in, const int* in_sizes, int n_in,
                              void* d_out, int out_size, void* d_ws, size_t ws_size,
                              hipStream_t stream) {
    const float* q  = (const float*)d_in[0];
    const float* k  = (const float*)d_in[1];
    const float* v  = (const float*)d_in[2];
    const float* Wq = (const float*)d_in[3];
    const float* Wk = (const float*)d_in[4];
    const float* Wv = (const float*)d_in[5];
    const float* Wo = (const float*)d_in[6];
    float* out = (float*)d_out;

    const size_t NW = (size_t)DMODEL * DMODEL;

    char* p = (char*)d_ws;
    f16* qh  = (f16*)p; p += NQ_ELEMS * 2;
    f16* kh  = (f16*)p; p += NKV_ELEMS * 2;
    f16* vh  = (f16*)p; p += NKV_ELEMS * 2;
    f16* WqT = (f16*)p; p += NW * 2;
    f16* WkT = (f16*)p; p += NW * 2;
    f16* WvT = (f16*)p; p += NW * 2;
    f16* WoT = (f16*)p; p += NW * 2;
    f16* Qh  = (f16*)p; p += NQ_ELEMS * 2;
    f16* Kh  = (f16*)p; p += NKV_ELEMS * 2;
    f16* Vh  = (f16*)p; p += NKV_ELEMS * 2;
    float* attnw = (float*)p; p += (size_t)B_ * LKV_ * NH * SPAN * 4;
    f16* ctxh = (f16*)p; p += NQ_ELEMS * 2;

    // 1) fused converts + weight transposes
    prep_all<<<dim3(17408), 256, 0, stream>>>(q, k, v, qh, kh, vh,
                                              Wq, Wk, Wv, Wo, WqT, WkT, WvT, WoT);

    // 2) Q/K/V projections fused, XCD-swizzled
    gemm_qkv<<<dim3(1024), 256, 0, stream>>>(qh, kh, vh, WqT, WkT, WvT, Qh, Kh, Vh);

    // 3) per-column masked scores + query-axis softmax
    attn_scores<<<dim3(LKV_ / 4, B_), 256, 0, stream>>>(Qh, Kh, attnw);

    // 4) per-query gather of weighted V
    ctx_gather<<<dim3(LQ_ / 16, B_), 256, 0, stream>>>(attnw, Vh, ctxh);

    // 5) output projection (f32 out), XCD-swizzled
    gemm_out<<<dim3(512), 256, 0, stream>>>(ctxh, WoT, out);
}

// Round 6
// 227.040 us; speedup vs baseline: 1.3778x; 1.0099x over previous
//
#include <hip/hip_runtime.h>
#include <cstdint>
#include <cstddef>

// ---------------------------------------------------------------------------
// SparseMHADecoder: B=2, LQ=4096, LKV=2048, D=1024, H=16, d=64, span=16, stride=2
// R6: fold the q/k/v f32->f16 convert INTO gemm_qkv's A-staging (A read as f32
//     from the original inputs, in-register cvt, ds_write to the same swizzled
//     LDS layout). Kills prep_all's 75MB round trip (~12us); prep shrinks to
//     the 4 weight transposes. B-side keeps the verified global_load_lds path.
// R5 carried: BK=64, XOR chunk swizzle, XCD swizzle, fp16 numerics.
// ---------------------------------------------------------------------------

typedef _Float16 f16;
typedef _Float16 f16x4 __attribute__((ext_vector_type(4)));
typedef _Float16 f16x8 __attribute__((ext_vector_type(8)));
typedef float v4f __attribute__((ext_vector_type(4)));

#define B_  2
#define LQ_ 4096
#define LKV_ 2048
#define DMODEL 1024
#define NH 16
#define HD 64
#define SPAN 16
#define STRIDE 2

#define NQ_ELEMS  ((size_t)B_ * LQ_ * DMODEL)   // 8388608
#define NKV_ELEMS ((size_t)B_ * LKV_ * DMODEL)  // 4194304

__device__ __forceinline__ void async_copy16(const f16* g, f16* l) {
    __builtin_amdgcn_global_load_lds((const __attribute__((address_space(1))) void*)g,
                                     (__attribute__((address_space(3))) void*)l, 16, 0, 0);
}

// ------------- prep: 4 weight transposes, Wt[n][k] = (f16)W[k][n] ------------
__global__ __launch_bounds__(256)
void transpose_all(const float* __restrict__ W0, const float* __restrict__ W1,
                   const float* __restrict__ W2, const float* __restrict__ W3,
                   f16* __restrict__ T0, f16* __restrict__ T1,
                   f16* __restrict__ T2, f16* __restrict__ T3) {
    const int t = threadIdx.x;
    const int bid = blockIdx.x;             // 1024 = 16x16 tiles x 4 weights
    const int z = bid >> 8, rem = bid & 255;
    const int bx = rem & 15, byy = rem >> 4;
    const float* W;
    f16* Wt;
    switch (z) {
        case 0: W = W0; Wt = T0; break;
        case 1: W = W1; Wt = T1; break;
        case 2: W = W2; Wt = T2; break;
        default: W = W3; Wt = T3; break;
    }
    __shared__ float tile[64][65];
    const int r0 = byy * 64, c0 = bx * 64;
    const int tx = t & 63, ty = t >> 6;     // (64,4)
    for (int i = ty; i < 64; i += 4)
        tile[i][tx] = W[(long)(r0 + i) * DMODEL + c0 + tx];
    __syncthreads();
    for (int i = ty; i < 64; i += 4)
        Wt[(long)(c0 + i) * DMODEL + r0 + tx] = (f16)tile[tx][i];
}

// ---------------- fp16 GEMM body, C[m][n] = sum_k A[m][k]*Bt[n][k] -----------
// 128x128 tile, BK=64, XOR chunk swizzle (R5-verified). A_F32: A is read as
// f32 from global, converted in-register, ds_write_b128 to the same layout.
template <bool OUT_F32, bool A_F32>
__device__ __forceinline__ void gemm_body(const void* __restrict__ Av,
                                          const f16* __restrict__ Bt,
                                          void* __restrict__ Cv,
                                          int rowTile, int colTile) {
    constexpr int K = DMODEL, N = DMODEL;
    __shared__ f16 As[128 * 64];
    __shared__ f16 Bs[128 * 64];
    const int t = threadIdx.x;
    const int lane = t & 63;
    const int w = t >> 6;
    const int wm = w >> 1, wn = w & 1;
    const long rowBase = (long)rowTile * 128;
    const long colBase = (long)colTile * 128;
    const int qrow = lane & 15;
    const int quad = lane >> 4;

    v4f acc[4][4] = {};

    // staging: thread t covers rows srow+32i (i=0..3), LDS chunk schunk holds
    // global chunk schunk^(srow&7) (8 f16 / 16B grangranularity)
    const int srow = t >> 3;          // 0..31
    const int schunk = t & 7;
    const int gchunk = schunk ^ (srow & 7);
    const f16* aptrH = (const f16*)Av + (rowBase + srow) * (long)K + gchunk * 8;
    const float* aptrF = (const float*)Av + (rowBase + srow) * (long)K + gchunk * 8;
    const f16* bptr = Bt + (colBase + srow) * (long)K + gchunk * 8;
    f16* lA = &As[srow * 64 + schunk * 8];
    f16* lB = &Bs[srow * 64 + schunk * 8];

    for (int k0 = 0; k0 < K; k0 += 64) {
#pragma unroll
        for (int i = 0; i < 4; ++i)
            async_copy16(bptr + k0 + i * 32 * (long)K, lB + i * 2048);
        if (A_F32) {
            // load f32, cvt in-register, write LDS (same swizzled layout)
            float4 lo[4], hi[4];
#pragma unroll
            for (int i = 0; i < 4; ++i) {
                lo[i] = *(const float4*)(aptrF + k0 + i * 32 * (long)K);
                hi[i] = *(const float4*)(aptrF + k0 + i * 32 * (long)K + 4);
            }
#pragma unroll
            for (int i = 0; i < 4; ++i) {
                f16x8 o = {(f16)lo[i].x, (f16)lo[i].y, (f16)lo[i].z, (f16)lo[i].w,
                           (f16)hi[i].x, (f16)hi[i].y, (f16)hi[i].z, (f16)hi[i].w};
                *(f16x8*)(lA + i * 2048) = o;
            }
        } else {
#pragma unroll
            for (int i = 0; i < 4; ++i)
                async_copy16(aptrH + k0 + i * 32 * (long)K, lA + i * 2048);
        }
        __syncthreads();  // drains vmcnt+lgkm: staged tile visible
#pragma unroll
        for (int s = 0; s < 2; ++s) {   // two K=32 MFMA steps per BK=64 tile
            const int xk = (s * 4 + quad) ^ (qrow & 7);  // swizzled chunk
            f16x8 af[4], bf[4];
#pragma unroll
            for (int mt = 0; mt < 4; ++mt)
                af[mt] = *(const f16x8*)(&As[(wm * 64 + mt * 16 + qrow) * 64 + xk * 8]);
#pragma unroll
            for (int nt = 0; nt < 4; ++nt)
                bf[nt] = *(const f16x8*)(&Bs[(wn * 64 + nt * 16 + qrow) * 64 + xk * 8]);
#pragma unroll
            for (int mt = 0; mt < 4; ++mt)
#pragma unroll
                for (int nt = 0; nt < 4; ++nt)
                    acc[mt][nt] = __builtin_amdgcn_mfma_f32_16x16x32_f16(
                        af[mt], bf[nt], acc[mt][nt], 0, 0, 0);
        }
        __syncthreads();  // all reads done before next stage overwrites
    }

    // C/D layout (m89-verified): row = quad*4 + r, col = lane&15
#pragma unroll
    for (int mt = 0; mt < 4; ++mt)
#pragma unroll
        for (int nt = 0; nt < 4; ++nt) {
            const long col = colBase + wn * 64 + nt * 16 + qrow;
#pragma unroll
            for (int r = 0; r < 4; ++r) {
                const long row = rowBase + wm * 64 + mt * 16 + quad * 4 + r;
                if (OUT_F32)
                    ((float*)Cv)[row * (long)N + col] = acc[mt][nt][r];
                else
                    ((f16*)Cv)[row * (long)N + col] = (f16)acc[mt][nt][r];
            }
        }
}

// Fused Q/K/V projection from the ORIGINAL f32 inputs, 1024 blocks,
// XCD-swizzled (R4-verified: FETCH -82%).
__global__ __launch_bounds__(256, 2)
void gemm_qkv(const float* __restrict__ A0, const float* __restrict__ A1,
              const float* __restrict__ A2, const f16* __restrict__ B0,
              const f16* __restrict__ B1, const f16* __restrict__ B2,
              f16* __restrict__ C0, f16* __restrict__ C1, f16* __restrict__ C2) {
    const int id = blockIdx.x;
    const int xcd = id & 7;
    const int g = id >> 3;            // 0..127
    const int ct = g & 7;             // col tile
    int rowIdx = (g >> 3) + xcd * 16; // 0..127
    const float* A;
    const f16* Bt;
    f16* C;
    if (rowIdx < 64) {
        A = A0; Bt = B0; C = C0;
    } else if (rowIdx < 96) {
        A = A1; Bt = B1; C = C1; rowIdx -= 64;
    } else {
        A = A2; Bt = B2; C = C2; rowIdx -= 96;
    }
    gemm_body<false, true>((const void*)A, Bt, (void*)C, rowIdx, ct);
}

__global__ __launch_bounds__(256, 2)
void gemm_out(const f16* __restrict__ A, const f16* __restrict__ Bt,
              float* __restrict__ C) {
    const int id = blockIdx.x;        // 512 blocks
    const int xcd = id & 7;
    const int g = id >> 3;            // 0..63
    const int ct = g & 7;
    const int rowIdx = (g >> 3) + xcd * 8;  // 0..63
    gemm_body<true, false>((const void*)A, Bt, (void*)C, rowIdx, ct);
}

// -------- per-column scores + softmax over the 16 valid query rows ----------
__global__ __launch_bounds__(256)
void attn_scores(const f16* __restrict__ Q, const f16* __restrict__ Km,
                 float* __restrict__ attnw) {
    const int c0 = blockIdx.x * 4, b = blockIdx.y;
    const int t = threadIdx.x;
    __shared__ f16 Qs[24 * 1032];   // rows 0..21 used; 49.5 KB
    __shared__ f16 Ks[4 * 1032];    // 8.25 KB

#pragma unroll
    for (int it = 0; it < 12; ++it) {
        const int ch = t + 256 * it;        // 24 rows x 128 chunks
        const int row = ch >> 7, off = (ch & 127) * 8;
        int qq = 2 * c0 + row;
        if (qq > LQ_ - 1) qq = LQ_ - 1;     // clamp staging; masked in score
        f16x8 x = *(const f16x8*)(Q + (size_t)(b * LQ_ + qq) * DMODEL + off);
        const int h = off >> 6, bb = (off >> 3) & 7;
        *(f16x8*)(&Qs[row * 1032 + h * 64 + ((bb + h) & 7) * 8]) = x;
    }
#pragma unroll
    for (int it = 0; it < 2; ++it) {
        const int ch = t + 256 * it;        // 4 rows x 128 chunks
        const int row = ch >> 7, off = (ch & 127) * 8;
        f16x8 x = *(const f16x8*)(Km + (size_t)(b * LKV_ + c0 + row) * DMODEL + off);
        const int h = off >> 6, bb = (off >> 3) & 7;
        *(f16x8*)(&Ks[row * 1032 + h * 64 + ((bb + h) & 7) * 8]) = x;
    }
    __syncthreads();

    const int h = t >> 4, j = t & 15;
#pragma unroll
    for (int ci = 0; ci < 4; ++ci) {
        const int c = c0 + ci;
        const int q = STRIDE * c + j;
        const int row = 2 * ci + j;
        float a = 0.f;
#pragma unroll
        for (int bb = 0; bb < 8; ++bb) {
            const int off = h * 64 + ((bb + h) & 7) * 8;
            f16x8 qv = *(const f16x8*)(&Qs[row * 1032 + off]);
            f16x8 kv = *(const f16x8*)(&Ks[ci * 1032 + off]);  // wave-broadcast
#pragma unroll
            for (int u = 0; u < 8; ++u) a += (float)qv[u] * (float)kv[u];
        }
        float s = (q < LQ_) ? a : -1e30f;
        float m = s;
#pragma unroll
        for (int o = 1; o < 16; o <<= 1) m = fmaxf(m, __shfl_xor(m, o, 64));
        float p = (q < LQ_) ? __expf(s - m) : 0.f;
        float sum = p;
#pragma unroll
        for (int o = 1; o < 16; o <<= 1) sum += __shfl_xor(sum, o, 64);
        attnw[(size_t)((b * LKV_ + c) * NH + h) * SPAN + j] = p / sum;
    }
}

// ---- ctx[b,q,h,:] = sum_i attn[b, q/2-i, h, (q&1)+2i] * V[b, q/2-i, h, :] ----
__global__ __launch_bounds__(256)
void ctx_gather(const float* __restrict__ attnw, const f16* __restrict__ V,
                f16* __restrict__ ctx) {
    const int q0 = blockIdx.x * 16, b = blockIdx.y;
    const int t = threadIdx.x;
    const int kbase = (q0 >> 1) - 7;
    __shared__ f16 Vs[16 * 1024];     // 32 KB
    __shared__ float A_lds[16 * 256]; // 16 KB

#pragma unroll
    for (int it = 0; it < 8; ++it) {
        const int ch = t + 256 * it;       // 16 rows x 128 chunks
        const int row = ch >> 7, off = (ch & 127) * 8;
        int k = kbase + row;
        k = (k < 0) ? 0 : ((k > LKV_ - 1) ? LKV_ - 1 : k);
        *(f16x8*)(&Vs[row * 1024 + off]) =
            *(const f16x8*)(V + (size_t)(b * LKV_ + k) * DMODEL + off);
    }
#pragma unroll
    for (int it = 0; it < 4; ++it) {
        const int ch = t + 256 * it;       // 16 rows x 64 chunks of 4 f32
        const int row = ch >> 6, off = (ch & 63) * 4;
        int k = kbase + row;
        k = (k < 0) ? 0 : ((k > LKV_ - 1) ? LKV_ - 1 : k);
        *(float4*)(&A_lds[row * 256 + off]) =
            *(const float4*)(attnw + (size_t)(b * LKV_ + k) * 256 + off);
    }
    __syncthreads();

    const int d = t & 63;
    const int hg = t >> 6;
#pragma unroll
    for (int ql = 0; ql < 16; ++ql) {
        const int q = q0 + ql;
        const int j0 = q & 1;
        float acc[4] = {0.f, 0.f, 0.f, 0.f};
#pragma unroll
        for (int i = 0; i < SPAN / STRIDE; ++i) {
            const int kq = (q >> 1) - i;
            if (kq < 0) break;
            const int rr = kq - kbase;
#pragma unroll
            for (int hh = 0; hh < 4; ++hh) {
                const int h = hg * 4 + hh;
                acc[hh] += A_lds[rr * 256 + h * 16 + j0 + 2 * i] *
                           (float)Vs[rr * 1024 + h * 64 + d];
            }
        }
        f16* crow = ctx + (size_t)(b * LQ_ + q) * DMODEL;
#pragma unroll
        for (int hh = 0; hh < 4; ++hh) {
            const int h = hg * 4 + hh;
            crow[h * HD + d] = (f16)acc[hh];
        }
    }
}

// ---------------------------------------------------------------------------
extern "C" void kernel_launch(void* const* d_in, const int* in_sizes, int n_in,
                              void* d_out, int out_size, void* d_ws, size_t ws_size,
                              hipStream_t stream) {
    const float* q  = (const float*)d_in[0];
    const float* k  = (const float*)d_in[1];
    const float* v  = (const float*)d_in[2];
    const float* Wq = (const float*)d_in[3];
    const float* Wk = (const float*)d_in[4];
    const float* Wv = (const float*)d_in[5];
    const float* Wo = (const float*)d_in[6];
    float* out = (float*)d_out;

    const size_t NW = (size_t)DMODEL * DMODEL;

    char* p = (char*)d_ws;
    f16* WqT = (f16*)p; p += NW * 2;
    f16* WkT = (f16*)p; p += NW * 2;
    f16* WvT = (f16*)p; p += NW * 2;
    f16* WoT = (f16*)p; p += NW * 2;
    f16* Qh  = (f16*)p; p += NQ_ELEMS * 2;
    f16* Kh  = (f16*)p; p += NKV_ELEMS * 2;
    f16* Vh  = (f16*)p; p += NKV_ELEMS * 2;
    float* attnw = (float*)p; p += (size_t)B_ * LKV_ * NH * SPAN * 4;
    f16* ctxh = (f16*)p; p += NQ_ELEMS * 2;

    // 1) weight transposes only (q/k/v convert folded into gemm_qkv)
    transpose_all<<<dim3(1024), 256, 0, stream>>>(Wq, Wk, Wv, Wo,
                                                  WqT, WkT, WvT, WoT);

    // 2) Q/K/V projections from f32 inputs, fused + XCD-swizzled
    gemm_qkv<<<dim3(1024), 256, 0, stream>>>(q, k, v, WqT, WkT, WvT, Qh, Kh, Vh);

    // 3) per-column masked scores + query-axis softmax
    attn_scores<<<dim3(LKV_ / 4, B_), 256, 0, stream>>>(Qh, Kh, attnw);

    // 4) per-query gather of weighted V
    ctx_gather<<<dim3(LQ_ / 16, B_), 256, 0, stream>>>(attnw, Vh, ctxh);

    // 5) output projection (f32 out), XCD-swizzled
    gemm_out<<<dim3(512), 256, 0, stream>>>(ctxh, WoT, out);
}